// Round 15
// baseline (83.360 us; speedup 1.0000x reference)
//
#include <hip/hip_runtime.h>
#include <stdint.h>

#define NROW 256
#define NV   128000
#define NV4  (NV / 4)
#define HALF_F4 (NV4 / 2)       // 16000 float4 per half-row
#define GCAP 4096
#define HCAP 2048               // per-half stage capacity
#define LOG2E 1.44269504088896340736f
#define TPB  1024
#define NG   2048               // select radix groups
#define TCAP 2048               // tie capacity

// ---- workspace layout (bytes) ----
#define WS_SLOTS  0                                        // f32[NROW*8] A0 A1 W0 W1 B0 B1 - -
#define WS_CNT    ((size_t)NROW * 8 * 4)                    // u32[NROW*2]
#define WS_BEST   (WS_CNT + (size_t)NROW * 2 * 4)           // u64[NROW*2]
#define WS_GATHER (WS_BEST + (size_t)NROW * 2 * 8)          // u64[NROW*4096]
#define WS_GU     (WS_GATHER + (size_t)NROW * GCAP * 8)     // f32[NROW*4096]
#define WS_NEEDED (WS_GU + (size_t)NROW * GCAP * 4)         // ~12.6 MB

__device__ __forceinline__ unsigned fenc(float f) {
    unsigned b = __float_as_uint(f);
    return b ^ (((unsigned)((int)b >> 31)) | 0x80000000u);
}
__device__ __forceinline__ float fdec(unsigned e) {
    unsigned m = ((int)e >= 0) ? 0xFFFFFFFFu : 0x80000000u;
    return __uint_as_float(e ^ m);
}

// monotone race key: log2(p/noise) + const = s*log2e - log2(-log2 u) + const
__device__ __forceinline__ unsigned long long race_key(float s, float u, unsigned idx) {
    float nl  = -__builtin_amdgcn_logf(u);
    float l2n = __builtin_amdgcn_logf(nl);
    float keyf = fmaf(s, LOG2E, -l2n);
    return ((unsigned long long)fenc(keyf) << 32) | (unsigned)(~idx);
}

__device__ __forceinline__ float qval(float s) {       // exp(s) * 2^-20
    return __builtin_amdgcn_exp2f(fmaf(s, LOG2E, -20.0f));
}

// Acklam inverse normal CDF (abs err ~1e-7 in z; window margin >> this)
__device__ float phi_inv(float p) {
    const float a1=-3.969683028665376e+01f, a2=2.209460984245205e+02f,
                a3=-2.759285104469687e+02f, a4=1.383577518672690e+02f,
                a5=-3.066479806614716e+01f, a6=2.506628277459239e+00f;
    const float b1=-5.447609879822406e+01f, b2=1.615858368580409e+02f,
                b3=-1.556989798598866e+02f, b4=6.680131188771972e+01f,
                b5=-1.328068155288572e+01f;
    const float c1=-7.784894002430293e-03f, c2=-3.223964580411365e-01f,
                c3=-2.400758277161838e+00f, c4=-2.549732539343734e+00f,
                c5=4.374664141464968e+00f,  c6=2.938163982698783e+00f;
    const float d1=7.784695709041462e-03f, d2=3.224671290700398e-01f,
                d3=2.445134137142996e+00f, d4=3.754408661907416e+00f;
    const float plow = 0.02425f, phigh = 1.0f - plow;
    float q, r, x;
    if (p < plow) {
        q = sqrtf(-2.0f * logf(p));
        x = (((((c1*q+c2)*q+c3)*q+c4)*q+c5)*q+c6) /
            ((((d1*q+d2)*q+d3)*q+d4)*q+1.0f);
    } else if (p <= phigh) {
        q = p - 0.5f; r = q * q;
        x = (((((a1*r+a2)*r+a3)*r+a4)*r+a5)*r+a6)*q /
            (((((b1*r+b2)*r+b3)*r+b4)*r+b5)*r+1.0f);
    } else {
        q = sqrtf(-2.0f * logf(1.0f - p));
        x = -(((((c1*q+c2)*q+c3)*q+c4)*q+c5)*q+c6) /
             ((((d1*q+d2)*q+d3)*q+d4)*q+1.0f);
    }
    return x;
}

// initial analytic window (depends only on sigma, topp)
__device__ __forceinline__ void init_window(float sigma, float topp,
                                            float* zl, float* zh) {
    float tc = fminf(fmaxf(topp, 1e-7f), 1.0f - 1e-7f);
    float z0 = sigma - phi_inv(tc);
    float cdf0 = 0.5f * erfcf(-z0 * 0.70710678f);
    const float WH = 1600.0f / 128000.0f;
    float cdfl = cdf0 - WH, cdfh = cdf0 + WH;
    *zl = (cdfl <= 1e-7f) ? -1e30f : phi_inv(cdfl);
    *zh = (cdfh >= 1.0f - 1e-7f) ? 1e30f : phi_inv(cdfh);
}

// ======= K1: 2 blocks/row, 32 waves/CU — stream half, bucket + race + stage =
__global__ __launch_bounds__(TPB, 8)
void k1_stream(const float* __restrict__ logits, const float* __restrict__ temps,
               const float* __restrict__ topps, const float* __restrict__ unoise,
               float* __restrict__ slots, unsigned* __restrict__ cnt,
               unsigned long long* __restrict__ best,
               unsigned long long* __restrict__ gather, float* __restrict__ gu)
{
    __shared__ unsigned long long lst[HCAP];   // 16 KB
    __shared__ unsigned lstU[HCAP];            //  8 KB
    __shared__ float wred[16];
    __shared__ unsigned long long wbb[16];
    __shared__ unsigned lcnt;
    __shared__ float sh_sLo, sh_sHi;

    const int row = blockIdx.x >> 1;
    const int sl  = blockIdx.x & 1;
    const int tid = threadIdx.x;
    const float invT = 1.0f / temps[row];
    if (tid == 0) {
        float zl, zh;
        init_window(invT, topps[row], &zl, &zh);
        sh_sLo = invT * zl; sh_sHi = invT * zh;
        lcnt = 0u;
    }
    __syncthreads();
    const float sLo = sh_sLo, sHi = sh_sHi;
    const float4* __restrict__ l4 =
        (const float4*)(logits + (size_t)row * NV) + sl * HALF_F4;
    const float4* __restrict__ u4 =
        (const float4*)(unoise + (size_t)row * NV) + sl * HALF_F4;
    const int ibase = sl * HALF_F4 * 4;

    unsigned long long mybest = 0ull;
    float aacc = 0.0f, wacc = 0.0f, bacc = 0.0f;

    auto proc4 = [&](float4 x, float4 uu, bool valid, int vidx) {
        float xs[4] = {x.x, x.y, x.z, x.w};
        float us[4] = {uu.x, uu.y, uu.z, uu.w};
        #pragma unroll
        for (int c = 0; c < 4; ++c) {
            if (!valid) continue;
            float s = xs[c] * invT;
            float q = qval(s);
            unsigned idx = (unsigned)(ibase + vidx * 4 + c);
            if (s >= sHi) {
                unsigned long long key = race_key(s, us[c], idx);
                if (key > mybest) mybest = key;
                aacc += q;
            } else if (s >= sLo) {
                wacc += q;
                unsigned pos = atomicAdd(&lcnt, 1u);
                if (pos < HCAP) {
                    lst[pos] = ((unsigned long long)fenc(s) << 32) | (unsigned)(~idx);
                    lstU[pos] = __float_as_uint(us[c]);
                }
            } else {
                bacc += q;
            }
        }
    };

    for (int v = tid; v < HALF_F4; v += 2 * TPB) {
        int v1 = v + TPB;
        bool g1 = v1 < HALF_F4;
        float4 x0 = l4[v];
        float4 u0 = u4[v];
        float4 x1 = l4[g1 ? v1 : v];
        float4 u1 = u4[g1 ? v1 : v];
        proc4(x0, u0, true, v);
        proc4(x1, u1, g1, v1);
    }

    // block reductions
    #pragma unroll
    for (int o = 32; o > 0; o >>= 1) {
        aacc += __shfl_down(aacc, o, 64);
        wacc += __shfl_down(wacc, o, 64);
        bacc += __shfl_down(bacc, o, 64);
        unsigned long long other = __shfl_down(mybest, o, 64);
        if (other > mybest) mybest = other;
    }
    if ((tid & 63) == 0) { wbb[tid >> 6] = mybest; }
    // A
    if ((tid & 63) == 0) wred[tid >> 6] = aacc;
    __syncthreads();
    if (tid == 0) {
        float sv = 0.0f;
        #pragma unroll
        for (int w = 0; w < TPB / 64; ++w) sv += wred[w];
        slots[row * 8 + sl] = sv;
        unsigned long long mb = wbb[0];
        #pragma unroll
        for (int w = 1; w < TPB / 64; ++w) if (wbb[w] > mb) mb = wbb[w];
        best[row * 2 + sl] = mb;
    }
    __syncthreads();
    if ((tid & 63) == 0) wred[tid >> 6] = wacc;
    __syncthreads();
    if (tid == 0) {
        float sv = 0.0f;
        #pragma unroll
        for (int w = 0; w < TPB / 64; ++w) sv += wred[w];
        slots[row * 8 + 2 + sl] = sv;
    }
    __syncthreads();
    if ((tid & 63) == 0) wred[tid >> 6] = bacc;
    __syncthreads();
    if (tid == 0) {
        float sv = 0.0f;
        #pragma unroll
        for (int w = 0; w < TPB / 64; ++w) sv += wred[w];
        slots[row * 8 + 4 + sl] = sv;
        cnt[row * 2 + sl] = lcnt;          // may exceed HCAP -> K2 retry
    }
    __syncthreads();
    // flush stage to private global segment
    unsigned nn = lcnt; if (nn > HCAP) nn = HCAP;
    unsigned long long* __restrict__ gseg = gather + (size_t)row * GCAP + sl * HCAP;
    float* __restrict__ useg = gu + (size_t)row * GCAP + sl * HCAP;
    for (unsigned i = tid; i < nn; i += TPB) {
        gseg[i] = lst[i];
        useg[i] = __uint_as_float(lstU[i]);
    }
}

// ======= K2: 1 block/row — verify, (rare) retry re-stream, select ===========
__global__ __launch_bounds__(TPB, 4)
void k2_select(const float* __restrict__ logits, const float* __restrict__ temps,
               const float* __restrict__ topps, const float* __restrict__ unoise,
               const float* __restrict__ slots, const unsigned* __restrict__ cnt,
               const unsigned long long* __restrict__ bestg,
               const unsigned long long* __restrict__ gather,
               const float* __restrict__ gu, int* __restrict__ out)
{
    __shared__ unsigned long long stage[GCAP];   // 32 KB
    __shared__ unsigned stageU[GCAP];            // 16 KB
    __shared__ float ms[NG];                     //  8 KB
    __shared__ float ssA[NG];                    //  8 KB
    __shared__ float ssB[NG];                    //  8 KB
    __shared__ unsigned long long tk[TCAP];      // 16 KB
    __shared__ unsigned tu[TCAP];                //  8 KB
    __shared__ float wred[16];
    __shared__ unsigned long long red_b[16];
    __shared__ unsigned lcnt;
    __shared__ float shP, shA, sh_sLo, sh_sHi, sh_zl, sh_zh;
    __shared__ int sh_ok;
    __shared__ int sh_gstar, sh_kst;
    __shared__ unsigned sh_kmin, sh_kmax, sh_tn;
    __shared__ float sh_above;

    const int row = blockIdx.x;
    const int tid = threadIdx.x;
    const float invT = 1.0f / temps[row];
    const float topp = topps[row];
    const float sigma = invT;

    // verify from slots
    const float A0 = slots[row * 8 + 0], A1 = slots[row * 8 + 1];
    const float W0 = slots[row * 8 + 2], W1 = slots[row * 8 + 3];
    const float B0 = slots[row * 8 + 4], B1 = slots[row * 8 + 5];
    const unsigned n0 = cnt[row * 2 + 0], n1 = cnt[row * 2 + 1];
    const float A = A0 + A1, W = W0 + W1, B = B0 + B1;
    const float P0 = topp * (A + W + B);
    unsigned long long mybest = 0ull;

    if (tid == 0) {
        float zl, zh;
        init_window(sigma, topp, &zl, &zh);
        sh_zl = zl; sh_zh = zh;
        sh_sLo = sigma * zl; sh_sHi = sigma * zh;
        shP = P0;
        bool okhi = (A <= P0);
        bool okn  = (n0 <= HCAP) && (n1 <= HCAP);
        bool oklo = (A + W > P0) || (zl <= -1e30f * 0.1f);
        sh_ok = (okhi && okn && oklo) ? 1 : 0;
        if (sh_ok) shA = A;
    }
    __syncthreads();
    const float P = shP;

    if (sh_ok) {
        // fast path: load gathered window into LDS
        if (tid == 0) lcnt = n0 + n1;
        const unsigned long long* __restrict__ g0 = gather + (size_t)row * GCAP;
        const float* __restrict__ uu0 = gu + (size_t)row * GCAP;
        for (unsigned i = tid; i < n0; i += TPB) {
            stage[i] = g0[i];
            stageU[i] = __float_as_uint(uu0[i]);
        }
        const unsigned long long* __restrict__ g1 = g0 + HCAP;
        const float* __restrict__ uu1 = uu0 + HCAP;
        for (unsigned i = tid; i < n1; i += TPB) {
            stage[n0 + i] = g1[i];
            stageU[n0 + i] = __float_as_uint(uu1[i]);
        }
        mybest = (tid == 0) ? max(bestg[row * 2], bestg[row * 2 + 1]) : 0ull;
        __syncthreads();
    } else {
        // rare path: full re-stream retry loop (round-13 machinery)
        const float4* __restrict__ l4 = (const float4*)(logits + (size_t)row * NV);
        const float4* __restrict__ u4 = (const float4*)(unoise + (size_t)row * NV);
        // adjust window once based on observed failure before first re-stream
        if (tid == 0) {
            float zl = sh_zl, zh = sh_zh;
            float width = zh - zl;
            if (!(width > 0.25f)) width = 0.25f;
            if (width > 8.0f) width = 8.0f;
            bool okhi = (A <= P);
            bool okn  = (n0 <= HCAP) && (n1 <= HCAP);
            if (!okhi)      { zl = zh; zh = zh + 2.0f * width; }
            else if (!okn)  { zl = (zl > zh - 6.0f) ? 0.5f * (zl + zh) : (zh - 6.0f); }
            else            { zh = zl; zl = zl - 2.0f * width; }
            sh_zl = zl; sh_zh = zh;
            sh_sLo = sigma * zl; sh_sHi = sigma * zh;
        }
        __syncthreads();
        for (int attempt = 0; attempt < 32; ++attempt) {
            if (tid == 0) lcnt = 0u;
            __syncthreads();
            const float sLo = sh_sLo, sHi = sh_sHi;
            mybest = 0ull;
            float aacc = 0.0f, wacc = 0.0f;
            for (int v = tid; v < NV4; v += 2 * TPB) {
                int v1 = v + TPB;
                bool g1v = v1 < NV4;
                float4 x0 = l4[v];
                float4 u0 = u4[v];
                float4 x1 = l4[g1v ? v1 : v];
                float4 u1 = u4[g1v ? v1 : v];
                float xs0[4] = {x0.x, x0.y, x0.z, x0.w};
                float us0[4] = {u0.x, u0.y, u0.z, u0.w};
                float xs1[4] = {x1.x, x1.y, x1.z, x1.w};
                float us1[4] = {u1.x, u1.y, u1.z, u1.w};
                #pragma unroll
                for (int c = 0; c < 4; ++c) {
                    float s = xs0[c] * invT;
                    unsigned idx = (unsigned)(v * 4 + c);
                    if (s >= sHi) {
                        unsigned long long key = race_key(s, us0[c], idx);
                        if (key > mybest) mybest = key;
                        aacc += qval(s);
                    } else if (s >= sLo) {
                        wacc += qval(s);
                        unsigned pos = atomicAdd(&lcnt, 1u);
                        if (pos < GCAP) {
                            stage[pos] = ((unsigned long long)fenc(s) << 32) | (unsigned)(~idx);
                            stageU[pos] = __float_as_uint(us0[c]);
                        }
                    }
                }
                #pragma unroll
                for (int c = 0; c < 4; ++c) {
                    if (g1v) {
                        float s = xs1[c] * invT;
                        unsigned idx = (unsigned)(v1 * 4 + c);
                        if (s >= sHi) {
                            unsigned long long key = race_key(s, us1[c], idx);
                            if (key > mybest) mybest = key;
                            aacc += qval(s);
                        } else if (s >= sLo) {
                            wacc += qval(s);
                            unsigned pos = atomicAdd(&lcnt, 1u);
                            if (pos < GCAP) {
                                stage[pos] = ((unsigned long long)fenc(s) << 32) | (unsigned)(~idx);
                                stageU[pos] = __float_as_uint(us1[c]);
                            }
                        }
                    }
                }
            }
            #pragma unroll
            for (int o = 32; o > 0; o >>= 1) {
                aacc += __shfl_down(aacc, o, 64);
                wacc += __shfl_down(wacc, o, 64);
            }
            if ((tid & 63) == 0) wred[tid >> 6] = aacc;
            __syncthreads();
            if (tid == 0) {
                float sA = 0.0f;
                #pragma unroll
                for (int w = 0; w < TPB / 64; ++w) sA += wred[w];
                shA = sA;
            }
            __syncthreads();
            if ((tid & 63) == 0) wred[tid >> 6] = wacc;
            __syncthreads();
            if (tid == 0) {
                float sW = 0.0f;
                #pragma unroll
                for (int w = 0; w < TPB / 64; ++w) sW += wred[w];
                unsigned n = lcnt;
                float Ac = shA;
                bool okhi = (Ac <= P);
                bool okn  = (n <= GCAP);
                bool oklo = (Ac + sW > P) || (sh_zl <= -1e29f);
                if (okhi && okn && oklo) sh_ok = 1;
                else {
                    float zl = sh_zl, zh = sh_zh;
                    float width = zh - zl;
                    if (!(width > 0.25f)) width = 0.25f;
                    if (width > 8.0f) width = 8.0f;
                    if (!okhi)      { zl = zh; zh = zh + 2.0f * width; }
                    else if (!okn)  { zl = (zl > zh - 6.0f) ? 0.5f * (zl + zh) : (zh - 6.0f); }
                    else            { zh = zl; zl = zl - 2.0f * width; }
                    sh_zl = zl; sh_zh = zh;
                    sh_sLo = sigma * zl; sh_sHi = sigma * zh;
                }
            }
            __syncthreads();
            if (sh_ok) break;
        }
    }

    // ---------------- select on window (proven machinery) -------------------
    if (tid == 0) {
        sh_gstar = -1; sh_tn = 0u; sh_kst = 0;
        sh_kmin = 0xFFFFFFFFu; sh_kmax = 0u;
    }
    for (int g = tid; g < NG; g += TPB) ms[g] = 0.0f;
    __syncthreads();

    unsigned n = lcnt; if (n > GCAP) n = GCAP;
    if (n > 0) {
        unsigned kmn = 0xFFFFFFFFu, kmx = 0u;
        for (unsigned p = tid; p < n; p += TPB) {
            unsigned k = (unsigned)(stage[p] >> 32);
            kmn = min(kmn, k); kmx = max(kmx, k);
        }
        atomicMin(&sh_kmin, kmn);
        atomicMax(&sh_kmax, kmx);
        __syncthreads();
        const unsigned kmin = sh_kmin;
        const unsigned span = sh_kmax - kmin;
        const int Lb = 32 - __clz(span);            // span==0 -> 0
        const int shft = (Lb > 11) ? (Lb - 11) : 0; // groups <= 2048

        for (unsigned p = tid; p < n; p += TPB) {
            unsigned key = (unsigned)(stage[p] >> 32);
            atomicAdd(&ms[(key - kmin) >> shft], qval(fdec(key)));
        }
        __syncthreads();

        for (int g = tid; g < NG; g += TPB) ssA[g] = ms[g];
        __syncthreads();
        float* src = ssA; float* dst = ssB;
        for (int d = 1; d < NG; d <<= 1) {
            for (int g = tid; g < NG; g += TPB)
                dst[g] = src[g] + ((g + d < NG) ? src[g + d] : 0.0f);
            __syncthreads();
            float* tm = src; src = dst; dst = tm;
        }
        const float Ac = shA;
        for (int g = tid; g < NG; g += TPB) {
            float SI  = src[g];
            float SI1 = (g + 1 < NG) ? src[g + 1] : 0.0f;
            if (Ac + SI > P && Ac + SI1 <= P) atomicMax(&sh_gstar, g);
        }
        __syncthreads();
        const int gstar = sh_gstar;
        if (tid == 0)
            sh_above = Ac + ((gstar >= 0 && gstar + 1 < NG) ? src[gstar + 1] : 0.0f);

        for (unsigned p = tid; p < n; p += TPB) {
            unsigned long long e = stage[p];
            unsigned key = (unsigned)(e >> 32);
            int g = (int)((key - kmin) >> shft);
            if (gstar < 0 || g > gstar) {
                unsigned idx = ~(unsigned)(e & 0xFFFFFFFFull);
                unsigned long long k2 =
                    race_key(fdec(key), __uint_as_float(stageU[p]), idx);
                if (k2 > mybest) mybest = k2;
            } else if (g == gstar) {
                unsigned t = atomicAdd(&sh_tn, 1u);
                if (t < TCAP) { tk[t] = e; tu[t] = stageU[p]; }
            }
        }
        __syncthreads();
        unsigned tn = sh_tn; if (tn > TCAP) tn = TCAP;
        if (gstar >= 0 && tn > 0u) {
            int N2 = 64; while (N2 < (int)tn) N2 <<= 1;
            for (int i = tid; i < N2; i += TPB)
                if (i >= (int)tn) { tk[i] = 0ull; tu[i] = 0u; }
            __syncthreads();
            for (int k = 2; k <= N2; k <<= 1) {
                for (int j2 = k >> 1; j2 > 0; j2 >>= 1) {
                    for (int i = tid; i < N2; i += TPB) {
                        int ixj = i ^ j2;
                        if (ixj > i) {
                            unsigned long long a = tk[i], b = tk[ixj];
                            if (((i & k) == 0) ? (a < b) : (a > b)) {
                                tk[i] = b; tk[ixj] = a;
                                unsigned ut = tu[i]; tu[i] = tu[ixj]; tu[ixj] = ut;
                            }
                        }
                    }
                    __syncthreads();
                }
            }
            for (int i = tid; i < N2; i += TPB)
                ssA[i] = (i < (int)tn) ? qval(fdec((unsigned)(tk[i] >> 32))) : 0.0f;
            __syncthreads();
            float* s1 = ssA; float* s2 = ssB;
            for (int d = 1; d < N2; d <<= 1) {
                for (int i = tid; i < N2; i += TPB)
                    s2[i] = s1[i] + ((i >= d) ? s1[i - d] : 0.0f);
                __syncthreads();
                float* tm = s1; s1 = s2; s2 = tm;
            }
            const float above = sh_above;
            for (int i = tid; i < (int)tn; i += TPB) {
                float excl = above + ((i == 0) ? 0.0f : s1[i - 1]);
                if (excl <= P) atomicMax(&sh_kst, i + 1);
            }
            __syncthreads();
            const int kst = sh_kst;
            for (int i = tid; i < kst; i += TPB) {
                unsigned idx = ~(unsigned)(tk[i] & 0xFFFFFFFFull);
                unsigned long long k2 =
                    race_key(fdec((unsigned)(tk[i] >> 32)), __uint_as_float(tu[i]), idx);
                if (k2 > mybest) mybest = k2;
            }
            __syncthreads();
        }
    }

    // final winner reduce
    #pragma unroll
    for (int o = 32; o > 0; o >>= 1) {
        unsigned long long other = __shfl_down(mybest, o, 64);
        if (other > mybest) mybest = other;
    }
    if ((tid & 63) == 0) red_b[tid >> 6] = mybest;
    __syncthreads();
    if (tid == 0) {
        unsigned long long m2 = red_b[0];
        #pragma unroll
        for (int w = 1; w < TPB / 64; ++w) if (red_b[w] > m2) m2 = red_b[w];
        out[row] = (int)(~(unsigned)(m2 & 0xFFFFFFFFull));
    }
}

// ===== fallback: proven round-13 single kernel (ws too small) ===============
__global__ __launch_bounds__(TPB, 4)
void sampler_all(const float* __restrict__ logits, const float* __restrict__ temps,
                 const float* __restrict__ topps, const float* __restrict__ unoise,
                 int* __restrict__ out)
{
    __shared__ unsigned long long stage[GCAP];
    __shared__ unsigned stageU[GCAP];
    __shared__ float ms[NG];
    __shared__ float ssA[NG];
    __shared__ float ssB[NG];
    __shared__ unsigned long long tk[TCAP];
    __shared__ unsigned tu[TCAP];
    __shared__ float wred[16];
    __shared__ unsigned long long red_b[16];
    __shared__ unsigned lcnt;
    __shared__ float shP, shA, sh_sLo, sh_sHi, sh_zl, sh_zh;
    __shared__ int sh_ok;
    __shared__ int sh_gstar, sh_kst;
    __shared__ unsigned sh_kmin, sh_kmax, sh_tn;
    __shared__ float sh_above;

    const int row = blockIdx.x;
    const int tid = threadIdx.x;
    const float invT = 1.0f / temps[row];
    const float topp = topps[row];
    const float4* __restrict__ l4 = (const float4*)(logits + (size_t)row * NV);
    const float4* __restrict__ u4 = (const float4*)(unoise + (size_t)row * NV);

    if (tid == 0) {
        float zl, zh;
        init_window(invT, topp, &zl, &zh);
        sh_zl = zl; sh_zh = zh;
        sh_sLo = invT * zl; sh_sHi = invT * zh;
        sh_ok = 0;
    }
    __syncthreads();
    const float sigma = invT;

    unsigned long long mybest = 0ull;
    for (int attempt = 0; attempt < 32; ++attempt) {
        if (tid == 0) lcnt = 0u;
        __syncthreads();
        const float sLo = sh_sLo, sHi = sh_sHi;
        mybest = 0ull;
        float aacc = 0.0f, wacc = 0.0f, bacc = 0.0f;
        for (int v = tid; v < NV4; v += 2 * TPB) {
            int v1 = v + TPB;
            bool g1 = v1 < NV4;
            float4 x0 = l4[v];
            float4 u0 = u4[v];
            float4 x1 = l4[g1 ? v1 : v];
            float4 u1 = u4[g1 ? v1 : v];
            float xs0[4] = {x0.x, x0.y, x0.z, x0.w};
            float us0[4] = {u0.x, u0.y, u0.z, u0.w};
            float xs1[4] = {x1.x, x1.y, x1.z, x1.w};
            float us1[4] = {u1.x, u1.y, u1.z, u1.w};
            #pragma unroll
            for (int c = 0; c < 4; ++c) {
                float s = xs0[c] * invT;
                float q = qval(s);
                unsigned idx = (unsigned)(v * 4 + c);
                if (s >= sHi) {
                    unsigned long long key = race_key(s, us0[c], idx);
                    if (key > mybest) mybest = key;
                    aacc += q;
                } else if (s >= sLo) {
                    wacc += q;
                    unsigned pos = atomicAdd(&lcnt, 1u);
                    if (pos < GCAP) {
                        stage[pos] = ((unsigned long long)fenc(s) << 32) | (unsigned)(~idx);
                        stageU[pos] = __float_as_uint(us0[c]);
                    }
                } else bacc += q;
            }
            #pragma unroll
            for (int c = 0; c < 4; ++c) {
                if (g1) {
                    float s = xs1[c] * invT;
                    float q = qval(s);
                    unsigned idx = (unsigned)(v1 * 4 + c);
                    if (s >= sHi) {
                        unsigned long long key = race_key(s, us1[c], idx);
                        if (key > mybest) mybest = key;
                        aacc += q;
                    } else if (s >= sLo) {
                        wacc += q;
                        unsigned pos = atomicAdd(&lcnt, 1u);
                        if (pos < GCAP) {
                            stage[pos] = ((unsigned long long)fenc(s) << 32) | (unsigned)(~idx);
                            stageU[pos] = __float_as_uint(us1[c]);
                        }
                    } else bacc += q;
                }
            }
        }
        #pragma unroll
        for (int o = 32; o > 0; o >>= 1) {
            aacc += __shfl_down(aacc, o, 64);
            wacc += __shfl_down(wacc, o, 64);
            bacc += __shfl_down(bacc, o, 64);
        }
        if ((tid & 63) == 0) wred[tid >> 6] = aacc;
        __syncthreads();
        if (tid == 0) {
            float sA = 0.0f;
            #pragma unroll
            for (int w = 0; w < TPB / 64; ++w) sA += wred[w];
            shA = sA;
        }
        __syncthreads();
        if ((tid & 63) == 0) wred[tid >> 6] = wacc;
        __syncthreads();
        float sW_bc = 0.0f;
        if (tid == 0) {
            #pragma unroll
            for (int w = 0; w < TPB / 64; ++w) sW_bc += wred[w];
        }
        __syncthreads();
        if ((tid & 63) == 0) wred[tid >> 6] = bacc;
        __syncthreads();
        if (tid == 0) {
            float sB = 0.0f;
            #pragma unroll
            for (int w = 0; w < TPB / 64; ++w) sB += wred[w];
            if (attempt == 0) shP = topp * (shA + sW_bc + sB);
            const float P = shP;
            unsigned n = lcnt;
            float A = shA;
            bool okhi = (A <= P);
            bool okn  = (n <= GCAP);
            bool oklo = (A + sW_bc > P) || (sh_zl <= -1e29f);
            if (okhi && okn && oklo) sh_ok = 1;
            else {
                float zl = sh_zl, zh = sh_zh;
                float width = zh - zl;
                if (!(width > 0.25f)) width = 0.25f;
                if (width > 8.0f) width = 8.0f;
                if (!okhi)      { zl = zh; zh = zh + 2.0f * width; }
                else if (!okn)  { zl = (zl > zh - 6.0f) ? 0.5f * (zl + zh) : (zh - 6.0f); }
                else            { zh = zl; zl = zl - 2.0f * width; }
                sh_zl = zl; sh_zh = zh;
                sh_sLo = sigma * zl; sh_sHi = sigma * zh;
            }
        }
        __syncthreads();
        if (sh_ok) break;
    }
    const float P = shP;

    if (tid == 0) {
        sh_gstar = -1; sh_tn = 0u; sh_kst = 0;
        sh_kmin = 0xFFFFFFFFu; sh_kmax = 0u;
    }
    for (int g = tid; g < NG; g += TPB) ms[g] = 0.0f;
    __syncthreads();

    unsigned n = lcnt; if (n > GCAP) n = GCAP;
    if (n > 0) {
        unsigned kmn = 0xFFFFFFFFu, kmx = 0u;
        for (unsigned p = tid; p < n; p += TPB) {
            unsigned k = (unsigned)(stage[p] >> 32);
            kmn = min(kmn, k); kmx = max(kmx, k);
        }
        atomicMin(&sh_kmin, kmn);
        atomicMax(&sh_kmax, kmx);
        __syncthreads();
        const unsigned kmin = sh_kmin;
        const unsigned span = sh_kmax - kmin;
        const int Lb = 32 - __clz(span);
        const int shft = (Lb > 11) ? (Lb - 11) : 0;

        for (unsigned p = tid; p < n; p += TPB) {
            unsigned key = (unsigned)(stage[p] >> 32);
            atomicAdd(&ms[(key - kmin) >> shft], qval(fdec(key)));
        }
        __syncthreads();

        for (int g = tid; g < NG; g += TPB) ssA[g] = ms[g];
        __syncthreads();
        float* src = ssA; float* dst = ssB;
        for (int d = 1; d < NG; d <<= 1) {
            for (int g = tid; g < NG; g += TPB)
                dst[g] = src[g] + ((g + d < NG) ? src[g + d] : 0.0f);
            __syncthreads();
            float* tm = src; src = dst; dst = tm;
        }
        const float A = shA;
        for (int g = tid; g < NG; g += TPB) {
            float SI  = src[g];
            float SI1 = (g + 1 < NG) ? src[g + 1] : 0.0f;
            if (A + SI > P && A + SI1 <= P) atomicMax(&sh_gstar, g);
        }
        __syncthreads();
        const int gstar = sh_gstar;
        if (tid == 0)
            sh_above = A + ((gstar >= 0 && gstar + 1 < NG) ? src[gstar + 1] : 0.0f);

        for (unsigned p = tid; p < n; p += TPB) {
            unsigned long long e = stage[p];
            unsigned key = (unsigned)(e >> 32);
            int g = (int)((key - kmin) >> shft);
            if (gstar < 0 || g > gstar) {
                unsigned idx = ~(unsigned)(e & 0xFFFFFFFFull);
                unsigned long long k2 =
                    race_key(fdec(key), __uint_as_float(stageU[p]), idx);
                if (k2 > mybest) mybest = k2;
            } else if (g == gstar) {
                unsigned t = atomicAdd(&sh_tn, 1u);
                if (t < TCAP) { tk[t] = e; tu[t] = stageU[p]; }
            }
        }
        __syncthreads();
        unsigned tn = sh_tn; if (tn > TCAP) tn = TCAP;
        if (gstar >= 0 && tn > 0u) {
            int N2 = 64; while (N2 < (int)tn) N2 <<= 1;
            for (int i = tid; i < N2; i += TPB)
                if (i >= (int)tn) { tk[i] = 0ull; tu[i] = 0u; }
            __syncthreads();
            for (int k = 2; k <= N2; k <<= 1) {
                for (int j2 = k >> 1; j2 > 0; j2 >>= 1) {
                    for (int i = tid; i < N2; i += TPB) {
                        int ixj = i ^ j2;
                        if (ixj > i) {
                            unsigned long long a = tk[i], b = tk[ixj];
                            if (((i & k) == 0) ? (a < b) : (a > b)) {
                                tk[i] = b; tk[ixj] = a;
                                unsigned ut = tu[i]; tu[i] = tu[ixj]; tu[ixj] = ut;
                            }
                        }
                    }
                    __syncthreads();
                }
            }
            for (int i = tid; i < N2; i += TPB)
                ssA[i] = (i < (int)tn) ? qval(fdec((unsigned)(tk[i] >> 32))) : 0.0f;
            __syncthreads();
            float* s1 = ssA; float* s2 = ssB;
            for (int d = 1; d < N2; d <<= 1) {
                for (int i = tid; i < N2; i += TPB)
                    s2[i] = s1[i] + ((i >= d) ? s1[i - d] : 0.0f);
                __syncthreads();
                float* tm = s1; s1 = s2; s2 = tm;
            }
            const float above = sh_above;
            for (int i = tid; i < (int)tn; i += TPB) {
                float excl = above + ((i == 0) ? 0.0f : s1[i - 1]);
                if (excl <= P) atomicMax(&sh_kst, i + 1);
            }
            __syncthreads();
            const int kst = sh_kst;
            for (int i = tid; i < kst; i += TPB) {
                unsigned idx = ~(unsigned)(tk[i] & 0xFFFFFFFFull);
                unsigned long long k2 =
                    race_key(fdec((unsigned)(tk[i] >> 32)), __uint_as_float(tu[i]), idx);
                if (k2 > mybest) mybest = k2;
            }
            __syncthreads();
        }
    }

    #pragma unroll
    for (int o = 32; o > 0; o >>= 1) {
        unsigned long long other = __shfl_down(mybest, o, 64);
        if (other > mybest) mybest = other;
    }
    if ((tid & 63) == 0) red_b[tid >> 6] = mybest;
    __syncthreads();
    if (tid == 0) {
        unsigned long long m2 = red_b[0];
        #pragma unroll
        for (int w = 1; w < TPB / 64; ++w) if (red_b[w] > m2) m2 = red_b[w];
        out[row] = (int)(~(unsigned)(m2 & 0xFFFFFFFFull));
    }
}

extern "C" void kernel_launch(void* const* d_in, const int* in_sizes, int n_in,
                              void* d_out, int out_size, void* d_ws, size_t ws_size,
                              hipStream_t stream) {
    const float* logits = (const float*)d_in[0];
    const float* temps  = (const float*)d_in[1];
    const float* topps  = (const float*)d_in[2];
    const float* unoise = (const float*)d_in[3];
    int* out = (int*)d_out;

    if (ws_size < WS_NEEDED) {
        hipLaunchKernelGGL(sampler_all, dim3(NROW), dim3(TPB), 0, stream,
                           logits, temps, topps, unoise, out);
        return;
    }

    char* ws = (char*)d_ws;
    float* slots = (float*)(ws + WS_SLOTS);
    unsigned* cnt = (unsigned*)(ws + WS_CNT);
    unsigned long long* best = (unsigned long long*)(ws + WS_BEST);
    unsigned long long* gather = (unsigned long long*)(ws + WS_GATHER);
    float* gu = (float*)(ws + WS_GU);

    hipLaunchKernelGGL(k1_stream, dim3(NROW * 2), dim3(TPB), 0, stream,
                       logits, temps, topps, unoise, slots, cnt, best, gather, gu);
    hipLaunchKernelGGL(k2_select, dim3(NROW), dim3(TPB), 0, stream,
                       logits, temps, topps, unoise, slots, cnt, best, gather, gu, out);
}

// Round 16
// 73.037 us; speedup vs baseline: 1.1413x; 1.1413x over previous
//
#include <hip/hip_runtime.h>
#include <stdint.h>

#define NROW 256
#define NV   128000
#define NV4  (NV / 4)
#define GCAP 4096
#define LOG2E 1.44269504088896340736f
#define TPB  1024
#define NG   2048               // select radix groups
#define TCAP 2048               // tie capacity

__device__ __forceinline__ unsigned fenc(float f) {
    unsigned b = __float_as_uint(f);
    return b ^ (((unsigned)((int)b >> 31)) | 0x80000000u);
}
__device__ __forceinline__ float fdec(unsigned e) {
    unsigned m = ((int)e >= 0) ? 0xFFFFFFFFu : 0x80000000u;
    return __uint_as_float(e ^ m);
}

// monotone race key: log2(p/noise) + const = s*log2e - log2(-log2 u) + const
__device__ __forceinline__ unsigned long long race_key(float s, float u, unsigned idx) {
    float nl  = -__builtin_amdgcn_logf(u);
    float l2n = __builtin_amdgcn_logf(nl);
    float keyf = fmaf(s, LOG2E, -l2n);
    return ((unsigned long long)fenc(keyf) << 32) | (unsigned)(~idx);
}

__device__ __forceinline__ float qval(float s) {       // exp(s) * 2^-20
    return __builtin_amdgcn_exp2f(fmaf(s, LOG2E, -20.0f));
}

// Acklam inverse normal CDF (abs err ~1e-7 in z; window margin >> this)
__device__ float phi_inv(float p) {
    const float a1=-3.969683028665376e+01f, a2=2.209460984245205e+02f,
                a3=-2.759285104469687e+02f, a4=1.383577518672690e+02f,
                a5=-3.066479806614716e+01f, a6=2.506628277459239e+00f;
    const float b1=-5.447609879822406e+01f, b2=1.615858368580409e+02f,
                b3=-1.556989798598866e+02f, b4=6.680131188771972e+01f,
                b5=-1.328068155288572e+01f;
    const float c1=-7.784894002430293e-03f, c2=-3.223964580411365e-01f,
                c3=-2.400758277161838e+00f, c4=-2.549732539343734e+00f,
                c5=4.374664141464968e+00f,  c6=2.938163982698783e+00f;
    const float d1=7.784695709041462e-03f, d2=3.224671290700398e-01f,
                d3=2.445134137142996e+00f, d4=3.754408661907416e+00f;
    const float plow = 0.02425f, phigh = 1.0f - plow;
    float q, r, x;
    if (p < plow) {
        q = sqrtf(-2.0f * logf(p));
        x = (((((c1*q+c2)*q+c3)*q+c4)*q+c5)*q+c6) /
            ((((d1*q+d2)*q+d3)*q+d4)*q+1.0f);
    } else if (p <= phigh) {
        q = p - 0.5f; r = q * q;
        x = (((((a1*r+a2)*r+a3)*r+a4)*r+a5)*r+a6)*q /
            (((((b1*r+b2)*r+b3)*r+b4)*r+b5)*r+1.0f);
    } else {
        q = sqrtf(-2.0f * logf(1.0f - p));
        x = -(((((c1*q+c2)*q+c3)*q+c4)*q+c5)*q+c6) /
             ((((d1*q+d2)*q+d3)*q+d4)*q+1.0f);
    }
    return x;
}

// == single kernel, single stream pass: A/W/B buckets + race + stage + select
__global__ __launch_bounds__(TPB, 4)
void sampler_all(const float* __restrict__ logits, const float* __restrict__ temps,
                 const float* __restrict__ topps, const float* __restrict__ unoise,
                 int* __restrict__ out)
{
    __shared__ unsigned long long stage[GCAP];   // 32 KB
    __shared__ unsigned stageU[GCAP];            // 16 KB
    __shared__ float ms[NG];                     //  8 KB
    __shared__ float ssA[NG];                    //  8 KB
    __shared__ float ssB[NG];                    //  8 KB
    __shared__ unsigned long long tk[TCAP];      // 16 KB
    __shared__ unsigned tu[TCAP];                //  8 KB
    __shared__ float wred[16];
    __shared__ unsigned long long red_b[16];
    __shared__ unsigned lcnt;
    __shared__ float shP, shA, sh_sLo, sh_sHi, sh_zl, sh_zh;
    __shared__ int sh_ok;
    __shared__ int sh_gstar, sh_kst;
    __shared__ unsigned sh_kmin, sh_kmax, sh_tn;
    __shared__ float sh_above;

    const int row = blockIdx.x;
    const int tid = threadIdx.x;
    const float invT = 1.0f / temps[row];
    const float topp = topps[row];
    const float4* __restrict__ l4 = (const float4*)(logits + (size_t)row * NV);
    const float4* __restrict__ u4 = (const float4*)(unoise + (size_t)row * NV);

    // window init (depends only on sigma, topp — NOT on Zq)
    if (tid == 0) {
        float sigma = invT;
        float tc = fminf(fmaxf(topp, 1e-7f), 1.0f - 1e-7f);
        float z0 = sigma - phi_inv(tc);               // mass-cut position
        float cdf0 = 0.5f * erfcf(-z0 * 0.70710678f); // Phi(z0)
        const float WH = 1600.0f / 128000.0f;
        float cdfl = cdf0 - WH, cdfh = cdf0 + WH;
        float zl = (cdfl <= 1e-7f) ? -1e30f : phi_inv(cdfl);
        float zh = (cdfh >= 1.0f - 1e-7f) ? 1e30f : phi_inv(cdfh);
        sh_zl = zl; sh_zh = zh;
        sh_sLo = sigma * zl; sh_sHi = sigma * zh;
        sh_ok = 0;
    }
    __syncthreads();
    const float sigma = invT;

    // ------- fused stream: buckets A/W/B + race + stage, verify + retry -----
    unsigned long long mybest = 0ull;
    for (int attempt = 0; attempt < 32; ++attempt) {
        if (tid == 0) lcnt = 0u;
        __syncthreads();
        const float sLo = sh_sLo, sHi = sh_sHi;
        mybest = 0ull;
        float aacc = 0.0f, wacc = 0.0f, bacc = 0.0f;
        for (int v = tid; v < NV4; v += 2 * TPB) {
            int v1 = v + TPB;
            bool g1 = v1 < NV4;
            float4 x0 = l4[v];
            float4 u0 = u4[v];
            float4 x1 = l4[g1 ? v1 : v];
            float4 u1 = u4[g1 ? v1 : v];
            float xs0[4] = {x0.x, x0.y, x0.z, x0.w};
            float us0[4] = {u0.x, u0.y, u0.z, u0.w};
            float xs1[4] = {x1.x, x1.y, x1.z, x1.w};
            float us1[4] = {u1.x, u1.y, u1.z, u1.w};
            #pragma unroll
            for (int c = 0; c < 4; ++c) {
                float s = xs0[c] * invT;
                float q = qval(s);
                unsigned idx = (unsigned)(v * 4 + c);
                if (s >= sHi) {
                    unsigned long long key = race_key(s, us0[c], idx);
                    if (key > mybest) mybest = key;
                    aacc += q;
                } else if (s >= sLo) {
                    wacc += q;
                    unsigned pos = atomicAdd(&lcnt, 1u);
                    if (pos < GCAP) {
                        stage[pos] = ((unsigned long long)fenc(s) << 32) | (unsigned)(~idx);
                        stageU[pos] = __float_as_uint(us0[c]);
                    }
                } else {
                    bacc += q;
                }
            }
            #pragma unroll
            for (int c = 0; c < 4; ++c) {
                if (g1) {
                    float s = xs1[c] * invT;
                    float q = qval(s);
                    unsigned idx = (unsigned)(v1 * 4 + c);
                    if (s >= sHi) {
                        unsigned long long key = race_key(s, us1[c], idx);
                        if (key > mybest) mybest = key;
                        aacc += q;
                    } else if (s >= sLo) {
                        wacc += q;
                        unsigned pos = atomicAdd(&lcnt, 1u);
                        if (pos < GCAP) {
                            stage[pos] = ((unsigned long long)fenc(s) << 32) | (unsigned)(~idx);
                            stageU[pos] = __float_as_uint(us1[c]);
                        }
                    } else {
                        bacc += q;
                    }
                }
            }
        }
        // reduce A, W, B (B only needed on attempt 0 to form P = topp*Zq)
        #pragma unroll
        for (int o = 32; o > 0; o >>= 1) {
            aacc += __shfl_down(aacc, o, 64);
            wacc += __shfl_down(wacc, o, 64);
            bacc += __shfl_down(bacc, o, 64);
        }
        if ((tid & 63) == 0) wred[tid >> 6] = aacc;
        __syncthreads();
        if (tid == 0) {
            float sA = 0.0f;
            #pragma unroll
            for (int w = 0; w < TPB / 64; ++w) sA += wred[w];
            shA = sA;
        }
        __syncthreads();
        if ((tid & 63) == 0) wred[tid >> 6] = wacc;
        __syncthreads();
        float sW_bc = 0.0f;
        if (tid == 0) {
            #pragma unroll
            for (int w = 0; w < TPB / 64; ++w) sW_bc += wred[w];
        }
        __syncthreads();
        if ((tid & 63) == 0) wred[tid >> 6] = bacc;
        __syncthreads();
        if (tid == 0) {
            float sB = 0.0f;
            #pragma unroll
            for (int w = 0; w < TPB / 64; ++w) sB += wred[w];
            if (attempt == 0) shP = topp * (shA + sW_bc + sB);  // exact Zq bucket sum
            const float P = shP;
            unsigned n = lcnt;
            float A = shA;
            bool okhi = (A <= P);
            bool okn  = (n <= GCAP);
            bool oklo = (A + sW_bc > P) || (sh_zl <= -1e29f);
            if (okhi && okn && oklo) sh_ok = 1;
            else {
                float zl = sh_zl, zh = sh_zh;
                float width = zh - zl;
                if (!(width > 0.25f)) width = 0.25f;
                if (width > 8.0f) width = 8.0f;
                if (!okhi)      { zl = zh; zh = zh + 2.0f * width; }   // cut above window
                else if (!okn)  { zl = (zl > zh - 6.0f) ? 0.5f * (zl + zh) : (zh - 6.0f); }
                else            { zh = zl; zl = zl - 2.0f * width; }   // cut below window
                sh_zl = zl; sh_zh = zh;
                sh_sLo = sigma * zl; sh_sHi = sigma * zh;
            }
        }
        __syncthreads();
        if (sh_ok) break;
    }
    const float P = shP;

    // ---------------- select on window (proven round-11/12 machinery) -------
    if (tid == 0) {
        sh_gstar = -1; sh_tn = 0u; sh_kst = 0;
        sh_kmin = 0xFFFFFFFFu; sh_kmax = 0u;
    }
    for (int g = tid; g < NG; g += TPB) ms[g] = 0.0f;
    __syncthreads();

    unsigned n = lcnt; if (n > GCAP) n = GCAP;
    if (n > 0) {
        unsigned kmn = 0xFFFFFFFFu, kmx = 0u;
        for (unsigned p = tid; p < n; p += TPB) {
            unsigned k = (unsigned)(stage[p] >> 32);
            kmn = min(kmn, k); kmx = max(kmx, k);
        }
        atomicMin(&sh_kmin, kmn);
        atomicMax(&sh_kmax, kmx);
        __syncthreads();
        const unsigned kmin = sh_kmin;
        const unsigned span = sh_kmax - kmin;
        const int Lb = 32 - __clz(span);            // span==0 -> 0
        const int shft = (Lb > 11) ? (Lb - 11) : 0; // groups <= 2048

        for (unsigned p = tid; p < n; p += TPB) {
            unsigned key = (unsigned)(stage[p] >> 32);
            atomicAdd(&ms[(key - kmin) >> shft], qval(fdec(key)));
        }
        __syncthreads();

        for (int g = tid; g < NG; g += TPB) ssA[g] = ms[g];
        __syncthreads();
        float* src = ssA; float* dst = ssB;
        for (int d = 1; d < NG; d <<= 1) {
            for (int g = tid; g < NG; g += TPB)
                dst[g] = src[g] + ((g + d < NG) ? src[g + d] : 0.0f);
            __syncthreads();
            float* tm = src; src = dst; dst = tm;
        }
        const float A = shA;
        for (int g = tid; g < NG; g += TPB) {
            float SI  = src[g];
            float SI1 = (g + 1 < NG) ? src[g + 1] : 0.0f;
            if (A + SI > P && A + SI1 <= P) atomicMax(&sh_gstar, g);
        }
        __syncthreads();
        const int gstar = sh_gstar;
        if (tid == 0)
            sh_above = A + ((gstar >= 0 && gstar + 1 < NG) ? src[gstar + 1] : 0.0f);

        for (unsigned p = tid; p < n; p += TPB) {
            unsigned long long e = stage[p];
            unsigned key = (unsigned)(e >> 32);
            int g = (int)((key - kmin) >> shft);
            if (gstar < 0 || g > gstar) {
                unsigned idx = ~(unsigned)(e & 0xFFFFFFFFull);
                unsigned long long k2 =
                    race_key(fdec(key), __uint_as_float(stageU[p]), idx);
                if (k2 > mybest) mybest = k2;
            } else if (g == gstar) {
                unsigned t = atomicAdd(&sh_tn, 1u);
                if (t < TCAP) { tk[t] = e; tu[t] = stageU[p]; }
            }
        }
        __syncthreads();
        unsigned tn = sh_tn; if (tn > TCAP) tn = TCAP;
        if (gstar >= 0 && tn > 0u) {
            int N2 = 64; while (N2 < (int)tn) N2 <<= 1;
            for (int i = tid; i < N2; i += TPB)
                if (i >= (int)tn) { tk[i] = 0ull; tu[i] = 0u; }
            __syncthreads();
            for (int k = 2; k <= N2; k <<= 1) {
                for (int j2 = k >> 1; j2 > 0; j2 >>= 1) {
                    for (int i = tid; i < N2; i += TPB) {
                        int ixj = i ^ j2;
                        if (ixj > i) {
                            unsigned long long a = tk[i], b = tk[ixj];
                            if (((i & k) == 0) ? (a < b) : (a > b)) {
                                tk[i] = b; tk[ixj] = a;
                                unsigned ut = tu[i]; tu[i] = tu[ixj]; tu[ixj] = ut;
                            }
                        }
                    }
                    __syncthreads();
                }
            }
            for (int i = tid; i < N2; i += TPB)
                ssA[i] = (i < (int)tn) ? qval(fdec((unsigned)(tk[i] >> 32))) : 0.0f;
            __syncthreads();
            float* s1 = ssA; float* s2 = ssB;
            for (int d = 1; d < N2; d <<= 1) {
                for (int i = tid; i < N2; i += TPB)
                    s2[i] = s1[i] + ((i >= d) ? s1[i - d] : 0.0f);
                __syncthreads();
                float* tm = s1; s1 = s2; s2 = tm;
            }
            const float above = sh_above;
            for (int i = tid; i < (int)tn; i += TPB) {
                float excl = above + ((i == 0) ? 0.0f : s1[i - 1]);
                if (excl <= P) atomicMax(&sh_kst, i + 1);
            }
            __syncthreads();
            const int kst = sh_kst;
            for (int i = tid; i < kst; i += TPB) {
                unsigned idx = ~(unsigned)(tk[i] & 0xFFFFFFFFull);
                unsigned long long k2 =
                    race_key(fdec((unsigned)(tk[i] >> 32)), __uint_as_float(tu[i]), idx);
                if (k2 > mybest) mybest = k2;
            }
            __syncthreads();
        }
    }

    // final winner reduce
    #pragma unroll
    for (int o = 32; o > 0; o >>= 1) {
        unsigned long long other = __shfl_down(mybest, o, 64);
        if (other > mybest) mybest = other;
    }
    if ((tid & 63) == 0) red_b[tid >> 6] = mybest;
    __syncthreads();
    if (tid == 0) {
        unsigned long long m2 = red_b[0];
        #pragma unroll
        for (int w = 1; w < TPB / 64; ++w) if (red_b[w] > m2) m2 = red_b[w];
        out[row] = (int)(~(unsigned)(m2 & 0xFFFFFFFFull));
    }
}

extern "C" void kernel_launch(void* const* d_in, const int* in_sizes, int n_in,
                              void* d_out, int out_size, void* d_ws, size_t ws_size,
                              hipStream_t stream) {
    const float* logits = (const float*)d_in[0];
    const float* temps  = (const float*)d_in[1];
    const float* topps  = (const float*)d_in[2];
    const float* unoise = (const float*)d_in[3];
    int* out = (int*)d_out;
    hipLaunchKernelGGL(sampler_all, dim3(NROW), dim3(TPB), 0, stream,
                       logits, temps, topps, unoise, out);
}